// Round 18
// baseline (381.047 us; speedup 1.0000x reference)
//
#include <hip/hip_runtime.h>

#define D 512
#define H 8
#define NL 3
#define FFD 2048
#define HID 256
#define BAND 17
#define BATCH 16
#define SEQ 512
#define MTOK (BATCH * SEQ)   // 8192
#define NOUT 101             // 12 + 89
#define NOUTP 128            // NOUT padded to 128 rows

typedef unsigned short u16;
typedef __attribute__((ext_vector_type(8))) short short8;     // bf16x8 MFMA frag
typedef __attribute__((ext_vector_type(4))) float f32x4;
typedef __attribute__((ext_vector_type(8))) unsigned short u16x8;

__device__ inline float bf2f(u16 u) {
    union { unsigned int i; float f; } x; x.i = ((unsigned int)u) << 16; return x.f;
}
__device__ inline u16 f2bf(float f) {
    union { float f; unsigned int i; } x; x.f = f;
    unsigned int r = x.i + 0x7fffu + ((x.i >> 16) & 1u);
    return (u16)(r >> 16);
}

// async global->LDS, 16B per lane; LDS dest = wave-uniform base + lane*16
__device__ __forceinline__ void gload_lds16(const u16* g, u16* l) {
    __builtin_amdgcn_global_load_lds(
        (const __attribute__((address_space(1))) unsigned int*)(g),
        (__attribute__((address_space(3))) unsigned int*)(l),
        16, 0, 0);
}

// ---------------------------------------------------------------------------
// bf16 MFMA GEMM body, 512 threads / 8 waves, 128x128 tile, BK=64, wave tile
// 64x32. 32 MFMA per barrier pair; 12 ds_read_b128 per 32 MFMA. 8-chunk XOR
// swizzle both sides (rule #21). Double-buffered LDS (2x32 KB), counted
// vmcnt(4). Measured best structure (rounds 10-17): 360.8 us total.
// Falsified: 64x64 wave tile (R7), no split-K (R11), BK=32 tri-buf
// single-barrier (R15), head fusion (R13) — do not revisit.
// ---------------------------------------------------------------------------
#define BM 128
#define BN 128
#define BK 64

__device__ __forceinline__ void gemm_body(
    const u16* __restrict__ A, int lda,
    const u16* __restrict__ B, int ldb,
    const float* __restrict__ bias, bool addb,
    float* __restrict__ Cf, int ldcf,
    u16* __restrict__ Cb, int ldcb,
    int N, int K, int relu, int kz, int m0, int n0,
    u16 (*As)[BM * BK], u16 (*Bs)[BN * BK])
{
    const int tid  = threadIdx.x;
    const int lane = tid & 63;
    const int wv   = tid >> 6;          // 0..7
    const int wr = wv >> 2, wc = wv & 3; // wave tile: 64 rows x 32 cols

    f32x4 acc[4][2] = {};

    const int srow8 = lane >> 3;                 // 0..7
    const int schunk = (lane & 7) ^ srow8;       // pre-swizzled source chunk
    const size_t aoff0 = (size_t)(m0 + wv * 16 + srow8) * lda + kz + schunk * 8;
    const size_t aoff1 = aoff0 + 8 * lda;
    const size_t boff0 = (size_t)(n0 + wv * 16 + srow8) * ldb + kz + schunk * 8;
    const size_t boff1 = boff0 + 8 * ldb;

    const int frow = lane & 15;
    const int q    = lane >> 4;                  // 0..3
    const int rc0 = ((q ^ (frow & 7)) << 3);           // kk=0 chunk*8
    const int rc1 = (((4 + q) ^ (frow & 7)) << 3);     // kk=1

    #define STAGE(buf, k0)                                                    \
        do {                                                                  \
            gload_lds16(A + aoff0 + (k0), &As[buf][(wv * 16 + 0) * BK]);      \
            gload_lds16(A + aoff1 + (k0), &As[buf][(wv * 16 + 8) * BK]);      \
            gload_lds16(B + boff0 + (k0), &Bs[buf][(wv * 16 + 0) * BK]);      \
            gload_lds16(B + boff1 + (k0), &Bs[buf][(wv * 16 + 8) * BK]);      \
        } while (0)

    #define COMPUTE(buf)                                                            \
        do {                                                                        \
            short8 af[4][2], bf[2][2];                                              \
            _Pragma("unroll")                                                       \
            for (int i = 0; i < 4; ++i) {                                           \
                const u16* rp = &As[buf][(wr * 64 + i * 16 + frow) * BK];           \
                af[i][0] = *(const short8*)&rp[rc0];                                \
                af[i][1] = *(const short8*)&rp[rc1];                                \
            }                                                                       \
            _Pragma("unroll")                                                       \
            for (int j = 0; j < 2; ++j) {                                           \
                const u16* rp = &Bs[buf][(wc * 32 + j * 16 + frow) * BK];           \
                bf[j][0] = *(const short8*)&rp[rc0];                                \
                bf[j][1] = *(const short8*)&rp[rc1];                                \
            }                                                                       \
            _Pragma("unroll")                                                       \
            for (int kk = 0; kk < 2; ++kk)                                          \
                _Pragma("unroll")                                                   \
                for (int i = 0; i < 4; ++i)                                         \
                    _Pragma("unroll")                                               \
                    for (int j = 0; j < 2; ++j)                                     \
                        acc[i][j] = __builtin_amdgcn_mfma_f32_16x16x32_bf16(        \
                            af[i][kk], bf[j][kk], acc[i][j], 0, 0, 0);              \
        } while (0)

    const int nt = K >> 6;
    STAGE(0, 0);
    int cur = 0;
    for (int t = 0; t < nt - 1; ++t) {
        STAGE(cur ^ 1, (t + 1) << 6);                    // prefetch next tile
        asm volatile("s_waitcnt vmcnt(4)" ::: "memory"); // cur landed; next in flight
        __builtin_amdgcn_s_barrier();
        __builtin_amdgcn_sched_barrier(0);
        COMPUTE(cur);
        __builtin_amdgcn_s_barrier();                    // all reads of buf done
        cur ^= 1;
    }
    asm volatile("s_waitcnt vmcnt(0)" ::: "memory");
    __builtin_amdgcn_s_barrier();
    __builtin_amdgcn_sched_barrier(0);
    COMPUTE(cur);

    #undef STAGE
    #undef COMPUTE

    // C/D layout: col = lane&15, row = (lane>>4)*4 + reg  [m89/m91]
    const int crow0 = (lane >> 4) * 4;
    const int ccol  = lane & 15;
    #pragma unroll
    for (int j = 0; j < 2; ++j) {
        int gcol = n0 + wc * 32 + j * 16 + ccol;
        if (gcol >= N) continue;
        float bv = addb ? bias[gcol] : 0.f;
        #pragma unroll
        for (int i = 0; i < 4; ++i) {
            #pragma unroll
            for (int r = 0; r < 4; ++r) {
                int grow = m0 + wr * 64 + i * 16 + crow0 + r;
                float v = acc[i][j][r] + bv;
                if (relu) v = fmaxf(v, 0.f);
                if (Cf) Cf[(size_t)grow * ldcf + gcol] = v;
                if (Cb) Cb[(size_t)grow * ldcb + gcol] = f2bf(v);
            }
        }
    }
}

// Standard wrapper: split-K (1/2/4) via blockIdx.z -> bf16 partials Cb0..Cb3;
// f32 out (Cf) for the head. Bijective XCD swizzle on (x,y); gridXY % 8 == 0.
__global__ __launch_bounds__(512) void gemm_kernel(
    const u16* __restrict__ A, int lda,
    const u16* __restrict__ B, int ldb,
    const float* __restrict__ bias,
    float* __restrict__ Cf, int ldcf,
    u16* __restrict__ Cb0, u16* __restrict__ Cb1,
    u16* __restrict__ Cb2, u16* __restrict__ Cb3, int ldcb,
    int M, int N, int K, int relu)
{
    __shared__ u16 As[2][BM * BK];   // 2 x 16 KB
    __shared__ u16 Bs[2][BN * BK];
    const int nb  = gridDim.x * gridDim.y;
    const int bid = blockIdx.y * gridDim.x + blockIdx.x;
    const int tile = (bid & 7) * (nb >> 3) + (bid >> 3);
    const int m0 = (tile / gridDim.x) * BM;
    const int n0 = (tile % gridDim.x) * BN;
    const int kz = blockIdx.z * K;
    u16* Cb = (blockIdx.z == 0) ? Cb0 : (blockIdx.z == 1) ? Cb1
            : (blockIdx.z == 2) ? Cb2 : Cb3;
    const bool addb = (bias != nullptr) && (blockIdx.z == 0);
    gemm_body(A, lda, B, ldb, bias, addb, Cf, ldcf, Cb, ldcb,
              N, K, relu, kz, m0, n0, As, Bs);
}

// Dual-job wrapper: blockIdx.z selects an independent GEMM job (both N=256,
// M=MTOK, no relu, bf16 out, full K). Overlaps the two input projections.
struct GemmJob { const u16* A; int lda; const u16* B; int ldb;
                 const float* bias; u16* Cb; int ldcb; int K; };
struct GemmDualArgs { GemmJob j[2]; };

__global__ __launch_bounds__(512) void gemm_dual_kernel(GemmDualArgs a)
{
    __shared__ u16 As[2][BM * BK];
    __shared__ u16 Bs[2][BN * BK];
    const GemmJob jb = a.j[blockIdx.z];
    const int nb  = gridDim.x * gridDim.y;
    const int bid = blockIdx.y * gridDim.x + blockIdx.x;
    const int tile = (bid & 7) * (nb >> 3) + (bid >> 3);
    const int m0 = (tile / gridDim.x) * BM;
    const int n0 = (tile % gridDim.x) * BN;
    gemm_body(jb.A, jb.lda, jb.B, jb.ldb, jb.bias, true, nullptr, 0,
              jb.Cb, jb.ldcb, 256, jb.K, 0, 0, m0, n0, As, Bs);
}

// ---------------------------------------------------------------------------
// MFMA banded attention. Block = (b, h, 128-query chunk), 512 threads, 8 waves.
// ---------------------------------------------------------------------------
#define CHUNK 128
#define KSLOT 144            // CHUNK + 16 key slots
#define VT_LD 152            // Vt row stride in u16 (+8 pad)

__global__ __launch_bounds__(512) void attn_kernel(
    const u16* __restrict__ qkv, const unsigned char* __restrict__ pad,
    u16* __restrict__ o)
{
    __shared__ u16 Vt[64 * VT_LD];        // V^T: [d][key slot]
    __shared__ u16 Pl[8 * 16 * 40];       // per-wave P tiles [16][40]
    __shared__ unsigned char padl[KSLOT];

    const int tid = threadIdx.x, lane = tid & 63, wv = tid >> 6;
    const int b = blockIdx.z, h = blockIdx.y, c0 = blockIdx.x * CHUNK;
    const u16* base = qkv + (size_t)b * SEQ * (3 * D);

    for (int s = tid; s < KSLOT * 4; s += 512) {
        int t = s >> 2, dq = (s & 3) * 16;
        int j = c0 - 16 + t; if (j < 0) j = 0;
        const u16* vrow = base + (size_t)j * (3 * D) + 2 * D + h * 64 + dq;
        u16 tmp[16];
        *(u16x8*)&tmp[0] = *(const u16x8*)&vrow[0];
        *(u16x8*)&tmp[8] = *(const u16x8*)&vrow[8];
        #pragma unroll
        for (int d = 0; d < 16; ++d)
            Vt[(dq + d) * VT_LD + t] = tmp[d];
    }
    if (tid < KSLOT) {
        int j = c0 - 16 + tid;
        padl[tid] = (j >= 0) ? pad[b * SEQ + j] : (unsigned char)1;
    }
    __syncthreads();

    const int qi0 = wv * 16;
    const int i0  = c0 + qi0;
    const int frow = lane & 15;
    const int g    = lane >> 4;
    const int kg8  = g * 8;
    const int g4   = g * 4;

    short8 qf[2];
    #pragma unroll
    for (int kk = 0; kk < 2; ++kk)
        qf[kk] = *(const short8*)&base[(size_t)(i0 + frow) * (3 * D) + h * 64 + kk * 32 + kg8];

    f32x4 sacc[2] = {};
    __builtin_amdgcn_s_setprio(1);
    #pragma unroll
    for (int jb = 0; jb < 2; ++jb) {
        int jrow = i0 - 16 + jb * 16 + frow; if (jrow < 0) jrow = 0;
        const u16* kbase = base + (size_t)jrow * (3 * D) + D + h * 64;
        #pragma unroll
        for (int kk = 0; kk < 2; ++kk) {
            short8 kf = *(const short8*)&kbase[kk * 32 + kg8];
            sacc[jb] = __builtin_amdgcn_mfma_f32_16x16x32_bf16(qf[kk], kf, sacc[jb], 0, 0, 0);
        }
    }
    __builtin_amdgcn_s_setprio(0);

    float sv[2][4];
    #pragma unroll
    for (int jb = 0; jb < 2; ++jb) {
        int s = jb * 16 + frow;
        int jg = i0 - 16 + s;
        bool padk = (jg < 0) || padl[qi0 + s];
        #pragma unroll
        for (int r = 0; r < 4; ++r) {
            int qq = g4 + r;
            bool banned = (s < qq) || (s > qq + 16) || padk;
            sv[jb][r] = sacc[jb][r] * 0.125f + (banned ? -1e9f : 0.f);
        }
    }

    float ex[2][4], rdn[4];
    #pragma unroll
    for (int r = 0; r < 4; ++r) {
        float m = fmaxf(sv[0][r], sv[1][r]);
        #pragma unroll
        for (int off = 1; off < 16; off <<= 1) m = fmaxf(m, __shfl_xor(m, off));
        float e0 = __expf(sv[0][r] - m);
        float e1 = __expf(sv[1][r] - m);
        float dsum = e0 + e1;
        #pragma unroll
        for (int off = 1; off < 16; off <<= 1) dsum += __shfl_xor(dsum, off);
        ex[0][r] = e0; ex[1][r] = e1;
        rdn[r] = 1.f / dsum;
    }

    u16* Pw = &Pl[wv * 640];
    #pragma unroll
    for (int jb = 0; jb < 2; ++jb)
        #pragma unroll
        for (int r = 0; r < 4; ++r)
            Pw[(g4 + r) * 40 + jb * 16 + frow] = f2bf(ex[jb][r]);
    short8 pa = *(const short8*)&Pw[frow * 40 + kg8];

    f32x4 oacc[4] = {};
    __builtin_amdgcn_s_setprio(1);
    #pragma unroll
    for (int nb = 0; nb < 4; ++nb) {
        short8 vf = *(const short8*)&Vt[(nb * 16 + frow) * VT_LD + qi0 + kg8];
        oacc[nb] = __builtin_amdgcn_mfma_f32_16x16x32_bf16(pa, vf, oacc[nb], 0, 0, 0);
    }
    __builtin_amdgcn_s_setprio(0);

    #pragma unroll
    for (int r = 0; r < 4; ++r) {
        size_t row = (size_t)(b * SEQ + i0 + g4 + r);
        #pragma unroll
        for (int nb = 0; nb < 4; ++nb)
            o[row * D + h * 64 + nb * 16 + frow] = f2bf(oacc[nb][r] * rdn[r]);
    }
}

// ---------------------------------------------------------------------------
// Fused residual + LayerNorm, all-bf16 streams, up to 4 delta partials:
// x = LN(bf2f(xin) + sum_i bf2f(d_i)) * g + bt; writes bf16. d2 nullable
// (d3 only read when d2 != null).
// ---------------------------------------------------------------------------
__global__ __launch_bounds__(256) void resln_kernel(
    const u16* __restrict__ xin,
    const u16* __restrict__ d0, const u16* __restrict__ d1,
    const u16* __restrict__ d2, const u16* __restrict__ d3,
    const float* __restrict__ g, const float* __restrict__ bt,
    u16* __restrict__ xb)
{
    int row  = blockIdx.x * 4 + (threadIdx.x >> 6);
    int lane = threadIdx.x & 63;
    size_t base = (size_t)row * D + lane * 8;
    u16x8 xv  = *(const u16x8*)(xin + base);
    u16x8 dv0 = *(const u16x8*)(d0 + base);
    u16x8 dv1 = *(const u16x8*)(d1 + base);

    float y[8];
    #pragma unroll
    for (int c = 0; c < 8; ++c)
        y[c] = bf2f(xv[c]) + bf2f(dv0[c]) + bf2f(dv1[c]);
    if (d2) {
        u16x8 dv2 = *(const u16x8*)(d2 + base);
        u16x8 dv3 = *(const u16x8*)(d3 + base);
        #pragma unroll
        for (int c = 0; c < 8; ++c)
            y[c] += bf2f(dv2[c]) + bf2f(dv3[c]);
    }
    float s = 0.f, s2 = 0.f;
    #pragma unroll
    for (int c = 0; c < 8; ++c) { s += y[c]; s2 += y[c] * y[c]; }
    #pragma unroll
    for (int off = 32; off > 0; off >>= 1) {
        s  += __shfl_xor(s, off);
        s2 += __shfl_xor(s2, off);
    }
    float mean = s * (1.f / D);
    float var  = s2 * (1.f / D) - mean * mean;
    float inv  = rsqrtf(fmaxf(var, 0.f) + 1e-5f);

    f32x4 gv0 = ((const f32x4*)g)[lane * 2],  gv1 = ((const f32x4*)g)[lane * 2 + 1];
    f32x4 bv0 = ((const f32x4*)bt)[lane * 2], bv1 = ((const f32x4*)bt)[lane * 2 + 1];
    u16x8 ob;
    #pragma unroll
    for (int c = 0; c < 4; ++c) {
        ob[c]     = f2bf((y[c] - mean) * inv * gv0[c] + bv0[c]);
        ob[c + 4] = f2bf((y[c + 4] - mean) * inv * gv1[c] + bv1[c]);
    }
    *(u16x8*)(xb + base) = ob;
}

// ---------------------------------------------------------------------------
// Batched conversions, flat grid with per-job block prefix. 8 elems/thread.
// mode 0: f32->bf16; mode 1: f32->f32; mode 2: f32->bf16 row-pad 300->320;
// mode 3: bf16 zero-fill; mode 5: pad-flag rows (1 iff all 300 cols == -1).
// ---------------------------------------------------------------------------
struct CvtJob { const float* src; u16* dstb; float* dstf; int n; int mode; };
struct CvtArgs { CvtJob j[16]; int blk0[17]; };

__global__ __launch_bounds__(256) void cvt_kernel(CvtArgs a) {
    const int bx = blockIdx.x;
    int jid = 0;
    #pragma unroll 1
    while (jid < 15 && bx >= a.blk0[jid + 1]) ++jid;
    const CvtJob jb = a.j[jid];

    if (jb.mode == 5) {
        int row  = (bx - a.blk0[jid]) * 4 + (threadIdx.x >> 6);
        int lane = threadIdx.x & 63;
        const f32x4* gr = (const f32x4*)(jb.src + (size_t)row * 300);
        bool any = false;
        for (int c4 = lane; c4 < 75; c4 += 64) {
            f32x4 v = gr[c4];
            any |= (v[0] != -1.f) | (v[1] != -1.f) | (v[2] != -1.f) | (v[3] != -1.f);
        }
        unsigned long long b = __ballot(any);
        if (lane == 0) ((unsigned char*)jb.dstb)[row] = (b == 0ull) ? 1 : 0;
        return;
    }

    const int i0 = (bx - a.blk0[jid]) * 2048 + threadIdx.x * 8;
    if (i0 >= jb.n) return;

    if (jb.mode == 0) {
        if (i0 + 8 <= jb.n) {
            f32x4 v0 = *(const f32x4*)(jb.src + i0);
            f32x4 v1 = *(const f32x4*)(jb.src + i0 + 4);
            u16x8 o;
            #pragma unroll
            for (int c = 0; c < 4; ++c) { o[c] = f2bf(v0[c]); o[c + 4] = f2bf(v1[c]); }
            *(u16x8*)(jb.dstb + i0) = o;
        } else {
            for (int e = 0; e < 8 && i0 + e < jb.n; ++e) jb.dstb[i0 + e] = f2bf(jb.src[i0 + e]);
        }
    } else if (jb.mode == 2) {
        int r = (int)((unsigned)i0 / 320u);
        int c = i0 - r * 320;
        const float* s = jb.src + (size_t)r * 300 + c;
        u16x8 o;
        if (c + 8 <= 300) {
            f32x4 v0 = *(const f32x4*)s;
            f32x4 v1 = *(const f32x4*)(s + 4);
            #pragma unroll
            for (int cc = 0; cc < 4; ++cc) { o[cc] = f2bf(v0[cc]); o[cc + 4] = f2bf(v1[cc]); }
        } else {
            #pragma unroll
            for (int e = 0; e < 8; ++e) o[e] = (c + e < 300) ? f2bf(s[e]) : (u16)0;
        }
        *(u16x8*)(jb.dstb + i0) = o;
    } else if (jb.mode == 1) {
        for (int e = 0; e < 8 && i0 + e < jb.n; ++e) jb.dstf[i0 + e] = jb.src[i0 + e];
    } else { // mode 3: zero fill (n multiple of 8)
        u16x8 z = {0, 0, 0, 0, 0, 0, 0, 0};
        *(u16x8*)(jb.dstb + i0) = z;
    }
}

// ---------------------------------------------------------------------------

extern "C" void kernel_launch(void* const* d_in, const int* in_sizes, int n_in,
                              void* d_out, int out_size, void* d_ws, size_t ws_size,
                              hipStream_t stream)
{
    const float* state  = (const float*)d_in[0];
    const float* goal   = (const float*)d_in[1];
    const float* W_obs  = (const float*)d_in[2];
    const float* b_obs  = (const float*)d_in[3];
    const float* W_lang = (const float*)d_in[4];
    const float* b_lang = (const float*)d_in[5];
    const float* W_in   = (const float*)d_in[6];
    const float* b_in   = (const float*)d_in[7];
    const float* Wqkv   = (const float*)d_in[8];
    const float* bqkv   = (const float*)d_in[9];
    const float* Wo     = (const float*)d_in[10];
    const float* bo     = (const float*)d_in[11];
    const float* W1     = (const float*)d_in[12];
    const float* b1     = (const float*)d_in[13];
    const float* W2     = (const float*)d_in[14];
    const float* b2     = (const float*)d_in[15];
    const float* g1     = (const float*)d_in[16];
    const float* bt1    = (const float*)d_in[17];
    const float* g2     = (const float*)d_in[18];
    const float* bt2    = (const float*)d_in[19];
    const float* W_outp = (const float*)d_in[20];
    const float* b_outp = (const float*)d_in[21];
    const float* W_a1   = (const float*)d_in[22];
    const float* b_a1   = (const float*)d_in[23];
    const float* W_a2   = (const float*)d_in[24];
    const float* b_a2   = (const float*)d_in[25];

    char* ws = (char*)d_ws;
    size_t off = 0;
    auto alloc = [&](size_t bytes) -> void* {
        void* p = ws + off;
        off = (off + bytes + 255) & ~(size_t)255;
        return p;
    };

    u16* wqkv_b  = (u16*)alloc((size_t)NL * 1536 * D * 2);
    u16* wo_b    = (u16*)alloc((size_t)NL * D * D * 2);
    u16* w1_b    = (u16*)alloc((size_t)NL * FFD * D * 2);
    u16* w2_b    = (u16*)alloc((size_t)NL * D * FFD * 2);
    u16* wobs_b  = (u16*)alloc((size_t)256 * 768 * 2);
    u16* wlang_b = (u16*)alloc((size_t)256 * 320 * 2);
    u16* win_b   = (u16*)alloc((size_t)D * D * 2);
    u16* woutp_b = (u16*)alloc((size_t)HID * D * 2);
    u16* wa_b    = (u16*)alloc((size_t)NOUTP * HID * 2);   // padded to 128 rows
    float* ba_f  = (float*)alloc((size_t)NOUT * 4);
    u16* state_b = (u16*)alloc((size_t)MTOK * 768 * 2);    // 12.6 MB \ after input
    u16* goal_b  = (u16*)alloc((size_t)MTOK * 320 * 2);    //  5.2 MB / stage: dead
    u16* feat_b  = (u16*)alloc((size_t)MTOK * D * 2);
    u16* x_b     = (u16*)alloc((size_t)MTOK * D * 2);
    u16* qkv_b   = (u16*)alloc((size_t)MTOK * 3 * D * 2);
    u16* o_b     = (u16*)alloc((size_t)MTOK * D * 2);
    u16* delta_b = (u16*)alloc((size_t)MTOK * D * 2);
    u16* delta3_b = (u16*)alloc((size_t)MTOK * D * 2);
    u16* delta4_b = (u16*)alloc((size_t)MTOK * D * 2);
    u16* h1_b    = (u16*)alloc((size_t)MTOK * FFD * 2);
    u16* hout_b  = (u16*)alloc((size_t)MTOK * HID * 2);
    unsigned char* pad_u8 = (unsigned char*)alloc(MTOK);
    // second split-K partial aliases the dead state_b region (12.6 MB >= 8.4 MB)
    u16* delta2_b = state_b;
    (void)ws_size; (void)in_sizes; (void)n_in; (void)out_size;

    // ---- conversions + pad flags (one batched launch, flat grid) ----
    CvtArgs ca;
    int nj = 0, blks = 0;
    auto addj = [&](const float* s, u16* db, float* df, int n, int mode, int nblk) {
        ca.j[nj].src = s; ca.j[nj].dstb = db; ca.j[nj].dstf = df;
        ca.j[nj].n = n; ca.j[nj].mode = mode;
        ca.blk0[nj] = blks;
        blks += nblk;
        ++nj;
    };
    auto addf = [&](const float* s, u16* db, float* df, int n, int mode) {
        addj(s, db, df, n, mode, (n + 2047) / 2048);
    };
    addf(state,  state_b, nullptr, MTOK * 768, 0);
    addf(goal,   goal_b,  nullptr, MTOK * 320, 2);
    addf(Wqkv,   wqkv_b,  nullptr, NL * 1536 * D, 0);
    addf(Wo,     wo_b,    nullptr, NL * D * D, 0);
    addf(W1,     w1_b,    nullptr, NL * FFD * D, 0);
    addf(W2,     w2_b,    nullptr, NL * D * FFD, 0);
    addf(W_obs,  wobs_b,  nullptr, 256 * 768, 0);
    addf(W_lang, wlang_b, nullptr, 256 * 320, 2);
    addf(W_in,   win_b,   nullptr, D * D, 0);
    addf(W_outp, woutp_b, nullptr, HID * D, 0);
    addf(W_a1,   wa_b,            nullptr, 12 * HID, 0);
    addf(W_a2,   wa_b + 12 * HID, nullptr, 89 * HID, 0);
    addf(nullptr, wa_b + NOUT * HID, nullptr, (NOUTP - NOUT) * HID, 3);
    addf(b_a1,   nullptr, ba_f,      12, 1);
    addf(b_a2,   nullptr, ba_f + 12, 89, 1);
    addj(goal,   (u16*)pad_u8, nullptr, MTOK, 5, MTOK / 4);   // pad flags
    ca.blk0[nj] = blks;
    cvt_kernel<<<blks, 256, 0, stream>>>(ca);

    // ksplit: 1 = normal (bf16 out Cb0, or f32 Cf); 2/4 = split-K bf16 partials
    auto gemm = [&](const u16* A, int lda, const u16* B, int ldb, const float* bias,
                    float* Cf, int ldcf, u16* Cb0, u16* Cb1, u16* Cb2, u16* Cb3,
                    int ldcb, int N, int K, int relu, int ksplit) {
        dim3 grid((N + BN - 1) / BN, MTOK / BM, ksplit);
        gemm_kernel<<<grid, 512, 0, stream>>>(A, lda, B, ldb, bias, Cf, ldcf,
                                              Cb0, Cb1, Cb2, Cb3, ldcb,
                                              MTOK, N, K / ksplit, relu);
    };

    // input projections -> feat (obs cols 0:256, lang cols 256:512) — one
    // dual-job dispatch, jobs run concurrently on different z-slices.
    {
        GemmDualArgs da;
        da.j[0] = { state_b, 768, wobs_b, 768, b_obs, feat_b,       D, 768 };
        da.j[1] = { goal_b,  320, wlang_b, 320, b_lang, feat_b + 256, D, 320 };
        dim3 grid(2, MTOK / BM, 2);
        gemm_dual_kernel<<<grid, 512, 0, stream>>>(da);
    }
    gemm(feat_b, D, win_b, D, b_in, nullptr, 0, x_b, nullptr, nullptr, nullptr,
         D, D, D, 0, 1);

    for (int l = 0; l < NL; ++l) {
        gemm(x_b, D, wqkv_b + (size_t)l * 1536 * D, D, bqkv + l * 1536,
             nullptr, 0, qkv_b, nullptr, nullptr, nullptr, 3 * D, 3 * D, D, 0, 1);
        {
            dim3 grid(SEQ / CHUNK, H, BATCH);
            attn_kernel<<<grid, 512, 0, stream>>>(qkv_b, pad_u8, o_b);
        }
        gemm(o_b, D, wo_b + (size_t)l * D * D, D, bo + l * D,
             nullptr, 0, delta_b, delta2_b, nullptr, nullptr, D, D, D, 0, 2);
        resln_kernel<<<MTOK / 4, 256, 0, stream>>>(x_b, delta_b, delta2_b,
                                                   nullptr, nullptr,
                                                   g1 + l * D, bt1 + l * D, x_b);
        gemm(x_b, D, w1_b + (size_t)l * FFD * D, D, b1 + l * FFD,
             nullptr, 0, h1_b, nullptr, nullptr, nullptr, FFD, FFD, D, 1, 1);
        gemm(h1_b, FFD, w2_b + (size_t)l * D * FFD, FFD, b2 + l * D,
             nullptr, 0, delta_b, delta2_b, delta3_b, delta4_b, D, D, FFD, 0, 4);
        resln_kernel<<<MTOK / 4, 256, 0, stream>>>(x_b, delta_b, delta2_b,
                                                   delta3_b, delta4_b,
                                                   g2 + l * D, bt2 + l * D, x_b);
    }

    // output head
    gemm(x_b, D, woutp_b, D, b_outp, nullptr, 0, hout_b, nullptr, nullptr, nullptr,
         HID, HID, D, 0, 1);
    gemm(hout_b, HID, wa_b, HID, ba_f, (float*)d_out, NOUT,
         nullptr, nullptr, nullptr, nullptr, 0, NOUT, HID, 0, 1);
}

// Round 19
// 359.261 us; speedup vs baseline: 1.0606x; 1.0606x over previous
//
#include <hip/hip_runtime.h>

#define D 512
#define H 8
#define NL 3
#define FFD 2048
#define HID 256
#define BAND 17
#define BATCH 16
#define SEQ 512
#define MTOK (BATCH * SEQ)   // 8192
#define NOUT 101             // 12 + 89
#define NOUTP 128            // NOUT padded to 128 rows

typedef unsigned short u16;
typedef __attribute__((ext_vector_type(8))) short short8;     // bf16x8 MFMA frag
typedef __attribute__((ext_vector_type(4))) float f32x4;
typedef __attribute__((ext_vector_type(8))) unsigned short u16x8;

__device__ inline float bf2f(u16 u) {
    union { unsigned int i; float f; } x; x.i = ((unsigned int)u) << 16; return x.f;
}
__device__ inline u16 f2bf(float f) {
    union { float f; unsigned int i; } x; x.f = f;
    unsigned int r = x.i + 0x7fffu + ((x.i >> 16) & 1u);
    return (u16)(r >> 16);
}

// async global->LDS, 16B per lane; LDS dest = wave-uniform base + lane*16
__device__ __forceinline__ void gload_lds16(const u16* g, u16* l) {
    __builtin_amdgcn_global_load_lds(
        (const __attribute__((address_space(1))) unsigned int*)(g),
        (__attribute__((address_space(3))) unsigned int*)(l),
        16, 0, 0);
}

// ---------------------------------------------------------------------------
// bf16 MFMA GEMM body, 512 threads / 8 waves, 128x128 tile, BK=64, wave tile
// 64x32. 32 MFMA per barrier pair; 12 ds_read_b128 per 32 MFMA. 8-chunk XOR
// swizzle both sides (rule #21). Double-buffered LDS (2x32 KB), counted
// vmcnt(4). Measured best structure (R17): 360.8 us total.
// Falsified: 64x64 wave tile (R7), split-K=1 (R11), split-K=4 (R18), BK=32
// tri-buf single-barrier (R15), head fusion (R13) — do not revisit.
// ---------------------------------------------------------------------------
#define BM 128
#define BN 128
#define BK 64

__device__ __forceinline__ void gemm_body(
    const u16* __restrict__ A, int lda,
    const u16* __restrict__ B, int ldb,
    const float* __restrict__ bias, bool addb,
    float* __restrict__ Cf, int ldcf,
    u16* __restrict__ Cb, int ldcb,
    int N, int K, int relu, int kz, int m0, int n0,
    u16 (*As)[BM * BK], u16 (*Bs)[BN * BK])
{
    const int tid  = threadIdx.x;
    const int lane = tid & 63;
    const int wv   = tid >> 6;          // 0..7
    const int wr = wv >> 2, wc = wv & 3; // wave tile: 64 rows x 32 cols

    f32x4 acc[4][2] = {};

    const int srow8 = lane >> 3;                 // 0..7
    const int schunk = (lane & 7) ^ srow8;       // pre-swizzled source chunk
    const size_t aoff0 = (size_t)(m0 + wv * 16 + srow8) * lda + kz + schunk * 8;
    const size_t aoff1 = aoff0 + 8 * lda;
    const size_t boff0 = (size_t)(n0 + wv * 16 + srow8) * ldb + kz + schunk * 8;
    const size_t boff1 = boff0 + 8 * ldb;

    const int frow = lane & 15;
    const int q    = lane >> 4;                  // 0..3
    const int rc0 = ((q ^ (frow & 7)) << 3);           // kk=0 chunk*8
    const int rc1 = (((4 + q) ^ (frow & 7)) << 3);     // kk=1

    #define STAGE(buf, k0)                                                    \
        do {                                                                  \
            gload_lds16(A + aoff0 + (k0), &As[buf][(wv * 16 + 0) * BK]);      \
            gload_lds16(A + aoff1 + (k0), &As[buf][(wv * 16 + 8) * BK]);      \
            gload_lds16(B + boff0 + (k0), &Bs[buf][(wv * 16 + 0) * BK]);      \
            gload_lds16(B + boff1 + (k0), &Bs[buf][(wv * 16 + 8) * BK]);      \
        } while (0)

    #define COMPUTE(buf)                                                            \
        do {                                                                        \
            short8 af[4][2], bf[2][2];                                              \
            _Pragma("unroll")                                                       \
            for (int i = 0; i < 4; ++i) {                                           \
                const u16* rp = &As[buf][(wr * 64 + i * 16 + frow) * BK];           \
                af[i][0] = *(const short8*)&rp[rc0];                                \
                af[i][1] = *(const short8*)&rp[rc1];                                \
            }                                                                       \
            _Pragma("unroll")                                                       \
            for (int j = 0; j < 2; ++j) {                                           \
                const u16* rp = &Bs[buf][(wc * 32 + j * 16 + frow) * BK];           \
                bf[j][0] = *(const short8*)&rp[rc0];                                \
                bf[j][1] = *(const short8*)&rp[rc1];                                \
            }                                                                       \
            _Pragma("unroll")                                                       \
            for (int kk = 0; kk < 2; ++kk)                                          \
                _Pragma("unroll")                                                   \
                for (int i = 0; i < 4; ++i)                                         \
                    _Pragma("unroll")                                               \
                    for (int j = 0; j < 2; ++j)                                     \
                        acc[i][j] = __builtin_amdgcn_mfma_f32_16x16x32_bf16(        \
                            af[i][kk], bf[j][kk], acc[i][j], 0, 0, 0);              \
        } while (0)

    const int nt = K >> 6;
    STAGE(0, 0);
    int cur = 0;
    for (int t = 0; t < nt - 1; ++t) {
        STAGE(cur ^ 1, (t + 1) << 6);                    // prefetch next tile
        asm volatile("s_waitcnt vmcnt(4)" ::: "memory"); // cur landed; next in flight
        __builtin_amdgcn_s_barrier();
        __builtin_amdgcn_sched_barrier(0);
        COMPUTE(cur);
        __builtin_amdgcn_s_barrier();                    // all reads of buf done
        cur ^= 1;
    }
    asm volatile("s_waitcnt vmcnt(0)" ::: "memory");
    __builtin_amdgcn_s_barrier();
    __builtin_amdgcn_sched_barrier(0);
    COMPUTE(cur);

    #undef STAGE
    #undef COMPUTE

    // C/D layout: col = lane&15, row = (lane>>4)*4 + reg  [m89/m91]
    const int crow0 = (lane >> 4) * 4;
    const int ccol  = lane & 15;
    #pragma unroll
    for (int j = 0; j < 2; ++j) {
        int gcol = n0 + wc * 32 + j * 16 + ccol;
        if (gcol >= N) continue;
        float bv = addb ? bias[gcol] : 0.f;
        #pragma unroll
        for (int i = 0; i < 4; ++i) {
            #pragma unroll
            for (int r = 0; r < 4; ++r) {
                int grow = m0 + wr * 64 + i * 16 + crow0 + r;
                float v = acc[i][j][r] + bv;
                if (relu) v = fmaxf(v, 0.f);
                if (Cf) Cf[(size_t)grow * ldcf + gcol] = v;
                if (Cb) Cb[(size_t)grow * ldcb + gcol] = f2bf(v);
            }
        }
    }
}

// Standard wrapper: split-K via blockIdx.z -> bf16 partials (Cb0/Cb1); f32
// out (Cf) for the head. Bijective XCD swizzle on (x,y); gridXY % 8 == 0.
__global__ __launch_bounds__(512) void gemm_kernel(
    const u16* __restrict__ A, int lda,
    const u16* __restrict__ B, int ldb,
    const float* __restrict__ bias,
    float* __restrict__ Cf, int ldcf,
    u16* __restrict__ Cb0, u16* __restrict__ Cb1, int ldcb,
    int M, int N, int K, int relu)
{
    __shared__ u16 As[2][BM * BK];   // 2 x 16 KB
    __shared__ u16 Bs[2][BN * BK];
    const int nb  = gridDim.x * gridDim.y;
    const int bid = blockIdx.y * gridDim.x + blockIdx.x;
    const int tile = (bid & 7) * (nb >> 3) + (bid >> 3);
    const int m0 = (tile / gridDim.x) * BM;
    const int n0 = (tile % gridDim.x) * BN;
    const int kz = blockIdx.z * K;
    u16* Cb = blockIdx.z ? Cb1 : Cb0;
    const bool addb = (bias != nullptr) && (blockIdx.z == 0);
    gemm_body(A, lda, B, ldb, bias, addb, Cf, ldcf, Cb, ldcb,
              N, K, relu, kz, m0, n0, As, Bs);
}

// Dual-job wrapper: blockIdx.z selects an independent GEMM job (both N=256,
// M=MTOK, no relu, bf16 out, full K). Overlaps the two input projections.
struct GemmJob { const u16* A; int lda; const u16* B; int ldb;
                 const float* bias; u16* Cb; int ldcb; int K; };
struct GemmDualArgs { GemmJob j[2]; };

__global__ __launch_bounds__(512) void gemm_dual_kernel(GemmDualArgs a)
{
    __shared__ u16 As[2][BM * BK];
    __shared__ u16 Bs[2][BN * BK];
    const GemmJob jb = a.j[blockIdx.z];
    const int nb  = gridDim.x * gridDim.y;
    const int bid = blockIdx.y * gridDim.x + blockIdx.x;
    const int tile = (bid & 7) * (nb >> 3) + (bid >> 3);
    const int m0 = (tile / gridDim.x) * BM;
    const int n0 = (tile % gridDim.x) * BN;
    gemm_body(jb.A, jb.lda, jb.B, jb.ldb, jb.bias, true, nullptr, 0,
              jb.Cb, jb.ldcb, 256, jb.K, 0, 0, m0, n0, As, Bs);
}

// ---------------------------------------------------------------------------
// MFMA banded attention. Block = (b, h, 128-query chunk), 512 threads, 8 waves.
// ---------------------------------------------------------------------------
#define CHUNK 128
#define KSLOT 144            // CHUNK + 16 key slots
#define VT_LD 152            // Vt row stride in u16 (+8 pad)

__global__ __launch_bounds__(512) void attn_kernel(
    const u16* __restrict__ qkv, const unsigned char* __restrict__ pad,
    u16* __restrict__ o)
{
    __shared__ u16 Vt[64 * VT_LD];        // V^T: [d][key slot]
    __shared__ u16 Pl[8 * 16 * 40];       // per-wave P tiles [16][40]
    __shared__ unsigned char padl[KSLOT];

    const int tid = threadIdx.x, lane = tid & 63, wv = tid >> 6;
    const int b = blockIdx.z, h = blockIdx.y, c0 = blockIdx.x * CHUNK;
    const u16* base = qkv + (size_t)b * SEQ * (3 * D);

    for (int s = tid; s < KSLOT * 4; s += 512) {
        int t = s >> 2, dq = (s & 3) * 16;
        int j = c0 - 16 + t; if (j < 0) j = 0;
        const u16* vrow = base + (size_t)j * (3 * D) + 2 * D + h * 64 + dq;
        u16 tmp[16];
        *(u16x8*)&tmp[0] = *(const u16x8*)&vrow[0];
        *(u16x8*)&tmp[8] = *(const u16x8*)&vrow[8];
        #pragma unroll
        for (int d = 0; d < 16; ++d)
            Vt[(dq + d) * VT_LD + t] = tmp[d];
    }
    if (tid < KSLOT) {
        int j = c0 - 16 + tid;
        padl[tid] = (j >= 0) ? pad[b * SEQ + j] : (unsigned char)1;
    }
    __syncthreads();

    const int qi0 = wv * 16;
    const int i0  = c0 + qi0;
    const int frow = lane & 15;
    const int g    = lane >> 4;
    const int kg8  = g * 8;
    const int g4   = g * 4;

    short8 qf[2];
    #pragma unroll
    for (int kk = 0; kk < 2; ++kk)
        qf[kk] = *(const short8*)&base[(size_t)(i0 + frow) * (3 * D) + h * 64 + kk * 32 + kg8];

    f32x4 sacc[2] = {};
    __builtin_amdgcn_s_setprio(1);
    #pragma unroll
    for (int jb = 0; jb < 2; ++jb) {
        int jrow = i0 - 16 + jb * 16 + frow; if (jrow < 0) jrow = 0;
        const u16* kbase = base + (size_t)jrow * (3 * D) + D + h * 64;
        #pragma unroll
        for (int kk = 0; kk < 2; ++kk) {
            short8 kf = *(const short8*)&kbase[kk * 32 + kg8];
            sacc[jb] = __builtin_amdgcn_mfma_f32_16x16x32_bf16(qf[kk], kf, sacc[jb], 0, 0, 0);
        }
    }
    __builtin_amdgcn_s_setprio(0);

    float sv[2][4];
    #pragma unroll
    for (int jb = 0; jb < 2; ++jb) {
        int s = jb * 16 + frow;
        int jg = i0 - 16 + s;
        bool padk = (jg < 0) || padl[qi0 + s];
        #pragma unroll
        for (int r = 0; r < 4; ++r) {
            int qq = g4 + r;
            bool banned = (s < qq) || (s > qq + 16) || padk;
            sv[jb][r] = sacc[jb][r] * 0.125f + (banned ? -1e9f : 0.f);
        }
    }

    float ex[2][4], rdn[4];
    #pragma unroll
    for (int r = 0; r < 4; ++r) {
        float m = fmaxf(sv[0][r], sv[1][r]);
        #pragma unroll
        for (int off = 1; off < 16; off <<= 1) m = fmaxf(m, __shfl_xor(m, off));
        float e0 = __expf(sv[0][r] - m);
        float e1 = __expf(sv[1][r] - m);
        float dsum = e0 + e1;
        #pragma unroll
        for (int off = 1; off < 16; off <<= 1) dsum += __shfl_xor(dsum, off);
        ex[0][r] = e0; ex[1][r] = e1;
        rdn[r] = 1.f / dsum;
    }

    u16* Pw = &Pl[wv * 640];
    #pragma unroll
    for (int jb = 0; jb < 2; ++jb)
        #pragma unroll
        for (int r = 0; r < 4; ++r)
            Pw[(g4 + r) * 40 + jb * 16 + frow] = f2bf(ex[jb][r]);
    short8 pa = *(const short8*)&Pw[frow * 40 + kg8];

    f32x4 oacc[4] = {};
    __builtin_amdgcn_s_setprio(1);
    #pragma unroll
    for (int nb = 0; nb < 4; ++nb) {
        short8 vf = *(const short8*)&Vt[(nb * 16 + frow) * VT_LD + qi0 + kg8];
        oacc[nb] = __builtin_amdgcn_mfma_f32_16x16x32_bf16(pa, vf, oacc[nb], 0, 0, 0);
    }
    __builtin_amdgcn_s_setprio(0);

    #pragma unroll
    for (int r = 0; r < 4; ++r) {
        size_t row = (size_t)(b * SEQ + i0 + g4 + r);
        #pragma unroll
        for (int nb = 0; nb < 4; ++nb)
            o[row * D + h * 64 + nb * 16 + frow] = f2bf(oacc[nb][r] * rdn[r]);
    }
}

// ---------------------------------------------------------------------------
// Fused residual + LayerNorm, all-bf16 streams:
// x = LN(bf2f(xin) + bf2f(d0) + bf2f(d1)) * g + bt; writes bf16.
// ---------------------------------------------------------------------------
__global__ __launch_bounds__(256) void resln_kernel(
    const u16* __restrict__ xin,
    const u16* __restrict__ d0, const u16* __restrict__ d1,
    const float* __restrict__ g, const float* __restrict__ bt,
    u16* __restrict__ xb)
{
    int row  = blockIdx.x * 4 + (threadIdx.x >> 6);
    int lane = threadIdx.x & 63;
    u16x8 xv = *(const u16x8*)(xin + (size_t)row * D + lane * 8);
    u16x8 dv0 = *(const u16x8*)(d0 + (size_t)row * D + lane * 8);
    u16x8 dv1 = *(const u16x8*)(d1 + (size_t)row * D + lane * 8);

    float y[8];
    float s = 0.f, s2 = 0.f;
    #pragma unroll
    for (int c = 0; c < 8; ++c) {
        y[c] = bf2f(xv[c]) + bf2f(dv0[c]) + bf2f(dv1[c]);
        s += y[c]; s2 += y[c] * y[c];
    }
    #pragma unroll
    for (int off = 32; off > 0; off >>= 1) {
        s  += __shfl_xor(s, off);
        s2 += __shfl_xor(s2, off);
    }
    float mean = s * (1.f / D);
    float var  = s2 * (1.f / D) - mean * mean;
    float inv  = rsqrtf(fmaxf(var, 0.f) + 1e-5f);

    f32x4 gv0 = ((const f32x4*)g)[lane * 2],  gv1 = ((const f32x4*)g)[lane * 2 + 1];
    f32x4 bv0 = ((const f32x4*)bt)[lane * 2], bv1 = ((const f32x4*)bt)[lane * 2 + 1];
    u16x8 ob;
    #pragma unroll
    for (int c = 0; c < 4; ++c) {
        ob[c]     = f2bf((y[c] - mean) * inv * gv0[c] + bv0[c]);
        ob[c + 4] = f2bf((y[c + 4] - mean) * inv * gv1[c] + bv1[c]);
    }
    *(u16x8*)(xb + (size_t)row * D + lane * 8) = ob;
}

// ---------------------------------------------------------------------------
// Batched conversions, flat grid with per-job block prefix. 8 elems/thread.
// mode 0: f32->bf16; mode 1: f32->f32; mode 2: f32->bf16 row-pad 300->320;
// mode 3: bf16 zero-fill; mode 5: pad-flag rows (1 iff all 300 cols == -1).
// ---------------------------------------------------------------------------
struct CvtJob { const float* src; u16* dstb; float* dstf; int n; int mode; };
struct CvtArgs { CvtJob j[16]; int blk0[17]; };

__global__ __launch_bounds__(256) void cvt_kernel(CvtArgs a) {
    const int bx = blockIdx.x;
    int jid = 0;
    #pragma unroll 1
    while (jid < 15 && bx >= a.blk0[jid + 1]) ++jid;
    const CvtJob jb = a.j[jid];

    if (jb.mode == 5) {
        int row  = (bx - a.blk0[jid]) * 4 + (threadIdx.x >> 6);
        int lane = threadIdx.x & 63;
        const f32x4* gr = (const f32x4*)(jb.src + (size_t)row * 300);
        bool any = false;
        for (int c4 = lane; c4 < 75; c4 += 64) {
            f32x4 v = gr[c4];
            any |= (v[0] != -1.f) | (v[1] != -1.f) | (v[2] != -1.f) | (v[3] != -1.f);
        }
        unsigned long long b = __ballot(any);
        if (lane == 0) ((unsigned char*)jb.dstb)[row] = (b == 0ull) ? 1 : 0;
        return;
    }

    const int i0 = (bx - a.blk0[jid]) * 2048 + threadIdx.x * 8;
    if (i0 >= jb.n) return;

    if (jb.mode == 0) {
        if (i0 + 8 <= jb.n) {
            f32x4 v0 = *(const f32x4*)(jb.src + i0);
            f32x4 v1 = *(const f32x4*)(jb.src + i0 + 4);
            u16x8 o;
            #pragma unroll
            for (int c = 0; c < 4; ++c) { o[c] = f2bf(v0[c]); o[c + 4] = f2bf(v1[c]); }
            *(u16x8*)(jb.dstb + i0) = o;
        } else {
            for (int e = 0; e < 8 && i0 + e < jb.n; ++e) jb.dstb[i0 + e] = f2bf(jb.src[i0 + e]);
        }
    } else if (jb.mode == 2) {
        int r = (int)((unsigned)i0 / 320u);
        int c = i0 - r * 320;
        const float* s = jb.src + (size_t)r * 300 + c;
        u16x8 o;
        if (c + 8 <= 300) {
            f32x4 v0 = *(const f32x4*)s;
            f32x4 v1 = *(const f32x4*)(s + 4);
            #pragma unroll
            for (int cc = 0; cc < 4; ++cc) { o[cc] = f2bf(v0[cc]); o[cc + 4] = f2bf(v1[cc]); }
        } else {
            #pragma unroll
            for (int e = 0; e < 8; ++e) o[e] = (c + e < 300) ? f2bf(s[e]) : (u16)0;
        }
        *(u16x8*)(jb.dstb + i0) = o;
    } else if (jb.mode == 1) {
        for (int e = 0; e < 8 && i0 + e < jb.n; ++e) jb.dstf[i0 + e] = jb.src[i0 + e];
    } else { // mode 3: zero fill (n multiple of 8)
        u16x8 z = {0, 0, 0, 0, 0, 0, 0, 0};
        *(u16x8*)(jb.dstb + i0) = z;
    }
}

// ---------------------------------------------------------------------------

extern "C" void kernel_launch(void* const* d_in, const int* in_sizes, int n_in,
                              void* d_out, int out_size, void* d_ws, size_t ws_size,
                              hipStream_t stream)
{
    const float* state  = (const float*)d_in[0];
    const float* goal   = (const float*)d_in[1];
    const float* W_obs  = (const float*)d_in[2];
    const float* b_obs  = (const float*)d_in[3];
    const float* W_lang = (const float*)d_in[4];
    const float* b_lang = (const float*)d_in[5];
    const float* W_in   = (const float*)d_in[6];
    const float* b_in   = (const float*)d_in[7];
    const float* Wqkv   = (const float*)d_in[8];
    const float* bqkv   = (const float*)d_in[9];
    const float* Wo     = (const float*)d_in[10];
    const float* bo     = (const float*)d_in[11];
    const float* W1     = (const float*)d_in[12];
    const float* b1     = (const float*)d_in[13];
    const float* W2     = (const float*)d_in[14];
    const float* b2     = (const float*)d_in[15];
    const float* g1     = (const float*)d_in[16];
    const float* bt1    = (const float*)d_in[17];
    const float* g2     = (const float*)d_in[18];
    const float* bt2    = (const float*)d_in[19];
    const float* W_outp = (const float*)d_in[20];
    const float* b_outp = (const float*)d_in[21];
    const float* W_a1   = (const float*)d_in[22];
    const float* b_a1   = (const float*)d_in[23];
    const float* W_a2   = (const float*)d_in[24];
    const float* b_a2   = (const float*)d_in[25];

    char* ws = (char*)d_ws;
    size_t off = 0;
    auto alloc = [&](size_t bytes) -> void* {
        void* p = ws + off;
        off = (off + bytes + 255) & ~(size_t)255;
        return p;
    };

    u16* wqkv_b  = (u16*)alloc((size_t)NL * 1536 * D * 2);
    u16* wo_b    = (u16*)alloc((size_t)NL * D * D * 2);
    u16* w1_b    = (u16*)alloc((size_t)NL * FFD * D * 2);
    u16* w2_b    = (u16*)alloc((size_t)NL * D * FFD * 2);
    u16* wobs_b  = (u16*)alloc((size_t)256 * 768 * 2);
    u16* wlang_b = (u16*)alloc((size_t)256 * 320 * 2);
    u16* win_b   = (u16*)alloc((size_t)D * D * 2);
    u16* woutp_b = (u16*)alloc((size_t)HID * D * 2);
    u16* wa_b    = (u16*)alloc((size_t)NOUTP * HID * 2);   // padded to 128 rows
    float* ba_f  = (float*)alloc((size_t)NOUT * 4);
    u16* state_b = (u16*)alloc((size_t)MTOK * 768 * 2);    // 12.6 MB \ after input
    u16* goal_b  = (u16*)alloc((size_t)MTOK * 320 * 2);    //  5.2 MB / stage: dead
    u16* feat_b  = (u16*)alloc((size_t)MTOK * D * 2);
    u16* x_b     = (u16*)alloc((size_t)MTOK * D * 2);
    u16* qkv_b   = (u16*)alloc((size_t)MTOK * 3 * D * 2);
    u16* o_b     = (u16*)alloc((size_t)MTOK * D * 2);
    u16* delta_b = (u16*)alloc((size_t)MTOK * D * 2);
    u16* h1_b    = (u16*)alloc((size_t)MTOK * FFD * 2);
    u16* hout_b  = (u16*)alloc((size_t)MTOK * HID * 2);
    unsigned char* pad_u8 = (unsigned char*)alloc(MTOK);
    // second split-K partial aliases the dead state_b region (12.6 MB >= 8.4 MB)
    u16* delta2_b = state_b;
    (void)ws_size; (void)in_sizes; (void)n_in; (void)out_size;

    // ---- conversions + pad flags (one batched launch, flat grid) ----
    CvtArgs ca;
    int nj = 0, blks = 0;
    auto addj = [&](const float* s, u16* db, float* df, int n, int mode, int nblk) {
        ca.j[nj].src = s; ca.j[nj].dstb = db; ca.j[nj].dstf = df;
        ca.j[nj].n = n; ca.j[nj].mode = mode;
        ca.blk0[nj] = blks;
        blks += nblk;
        ++nj;
    };
    auto addf = [&](const float* s, u16* db, float* df, int n, int mode) {
        addj(s, db, df, n, mode, (n + 2047) / 2048);
    };
    addf(state,  state_b, nullptr, MTOK * 768, 0);
    addf(goal,   goal_b,  nullptr, MTOK * 320, 2);
    addf(Wqkv,   wqkv_b,  nullptr, NL * 1536 * D, 0);
    addf(Wo,     wo_b,    nullptr, NL * D * D, 0);
    addf(W1,     w1_b,    nullptr, NL * FFD * D, 0);
    addf(W2,     w2_b,    nullptr, NL * D * FFD, 0);
    addf(W_obs,  wobs_b,  nullptr, 256 * 768, 0);
    addf(W_lang, wlang_b, nullptr, 256 * 320, 2);
    addf(W_in,   win_b,   nullptr, D * D, 0);
    addf(W_outp, woutp_b, nullptr, HID * D, 0);
    addf(W_a1,   wa_b,            nullptr, 12 * HID, 0);
    addf(W_a2,   wa_b + 12 * HID, nullptr, 89 * HID, 0);
    addf(nullptr, wa_b + NOUT * HID, nullptr, (NOUTP - NOUT) * HID, 3);
    addf(b_a1,   nullptr, ba_f,      12, 1);
    addf(b_a2,   nullptr, ba_f + 12, 89, 1);
    addj(goal,   (u16*)pad_u8, nullptr, MTOK, 5, MTOK / 4);   // pad flags
    ca.blk0[nj] = blks;
    cvt_kernel<<<blks, 256, 0, stream>>>(ca);

    // ksplit: 1 = normal (bf16 out Cb0, or f32 Cf); 2 = split-K bf16 halves
    auto gemm = [&](const u16* A, int lda, const u16* B, int ldb, const float* bias,
                    float* Cf, int ldcf, u16* Cb0, u16* Cb1, int ldcb,
                    int N, int K, int relu, int ksplit) {
        dim3 grid((N + BN - 1) / BN, MTOK / BM, ksplit);
        gemm_kernel<<<grid, 512, 0, stream>>>(A, lda, B, ldb, bias, Cf, ldcf,
                                              Cb0, Cb1, ldcb, MTOK, N, K / ksplit, relu);
    };

    // input projections -> feat (obs cols 0:256, lang cols 256:512) — one
    // dual-job dispatch, jobs run concurrently on different z-slices.
    {
        GemmDualArgs da;
        da.j[0] = { state_b, 768, wobs_b, 768, b_obs, feat_b,       D, 768 };
        da.j[1] = { goal_b,  320, wlang_b, 320, b_lang, feat_b + 256, D, 320 };
        dim3 grid(2, MTOK / BM, 2);
        gemm_dual_kernel<<<grid, 512, 0, stream>>>(da);
    }
    gemm(feat_b, D, win_b, D, b_in, nullptr, 0, x_b, nullptr, D, D, D, 0, 1);

    for (int l = 0; l < NL; ++l) {
        gemm(x_b, D, wqkv_b + (size_t)l * 1536 * D, D, bqkv + l * 1536,
             nullptr, 0, qkv_b, nullptr, 3 * D, 3 * D, D, 0, 1);
        {
            dim3 grid(SEQ / CHUNK, H, BATCH);
            attn_kernel<<<grid, 512, 0, stream>>>(qkv_b, pad_u8, o_b);
        }
        gemm(o_b, D, wo_b + (size_t)l * D * D, D, bo + l * D,
             nullptr, 0, delta_b, delta2_b, D, D, D, 0, 2);
        resln_kernel<<<MTOK / 4, 256, 0, stream>>>(x_b, delta_b, delta2_b,
                                                   g1 + l * D, bt1 + l * D, x_b);
        gemm(x_b, D, w1_b + (size_t)l * FFD * D, D, b1 + l * FFD,
             nullptr, 0, h1_b, nullptr, FFD, FFD, D, 1, 1);
        gemm(h1_b, FFD, w2_b + (size_t)l * D * FFD, FFD, b2 + l * D,
             nullptr, 0, delta_b, delta2_b, D, D, FFD, 0, 2);
        resln_kernel<<<MTOK / 4, 256, 0, stream>>>(x_b, delta_b, delta2_b,
                                                   g2 + l * D, bt2 + l * D, x_b);
    }

    // output head
    gemm(x_b, D, woutp_b, D, b_outp, nullptr, 0, hout_b, nullptr, HID, HID, D, 0, 1);
    gemm(hout_b, HID, wa_b, HID, ba_f, (float*)d_out, NOUT, nullptr, nullptr, 0, NOUT, HID, 0, 1);
}